// Round 12
// baseline (117.896 us; speedup 1.0000x reference)
//
#include <hip/hip_runtime.h>
#include <hip/hip_bf16.h>
#include <stdint.h>

// x[L=512][N=64][D=512] f32, upfold[O=512][N=64][D=512] f32
//   S[l,o,n] = sum_d x[l,n,d]*up[o,n,d] / sqrt(512);  W = sigmoid(S)-0.5
//   out[l,n,d] = sum_o W[l,o,n] * up[o,n,d]   (f32)
//
// Full tier (round 12 — best-of assembly):
//   kPrepU : ub[n][o][d] bf16 <- up   (streaming permutation, ~16 us)
//   kPrepX : xb[n][l][d] bf16 <- x    (streaming permutation, ~16 us)
//   kPrepT : ut[n][d][o] bf16 <- ub   (tiled transpose, 1KB writes, ~13 us)
//   kGemmP<1>: W[n][l][o] = sig(xb . ub^T /sqrt(D)) - 0.5   (round-8 schedule)
//   kGemmP<2>: out[l][n][d] = W . ut^T                      (round-8 schedule)
// GEMM: 256^2 tile, 512 thr / 8 waves, BK=32, 4 LDS buffers, counted
// vmcnt(8) (T4), swizzle involution chunk^=(row>>1)&3, XCD n-grouping.
// Lesson locked in (r7, r11): per-element f32->bf16 conversion belongs in a
// streaming prep kernel, NOT reg-staged inside the GEMM loop.

typedef __attribute__((ext_vector_type(8))) short short8;   // 8 bf16
typedef __attribute__((ext_vector_type(4))) float f32x4;

__device__ __forceinline__ uint16_t f2bf(float f) {
    uint32_t u = __builtin_bit_cast(uint32_t, f);
    uint32_t r = u + 0x7FFFu + ((u >> 16) & 1u);   // RNE
    return (uint16_t)(r >> 16);
}
__device__ __forceinline__ uint32_t cvt2(float a, float b) {
    return (uint32_t)f2bf(a) | ((uint32_t)f2bf(b) << 16);
}

// ---------------- kPrepU: ub[n][o][d] <- up[o][n][d], streaming ---------------
__global__ __launch_bounds__(256) void kPrepU(const float* __restrict__ up,
                                              uint16_t* __restrict__ ub) {
    int blk  = blockIdx.x;
    int rest = blk >> 3;                  // 0..1023
    int n    = (blk & 7) * 8 + (rest >> 7);
    int o    = (rest & 127) * 4 + (threadIdx.x >> 6);
    int d0   = (threadIdx.x & 63) * 8;
    const float* src = up + ((size_t)o * 64 + n) * 512 + d0;
    float4 v0 = *reinterpret_cast<const float4*>(src);
    float4 v1 = *reinterpret_cast<const float4*>(src + 4);
    uint32_t pk[4] = {cvt2(v0.x, v0.y), cvt2(v0.z, v0.w),
                      cvt2(v1.x, v1.y), cvt2(v1.z, v1.w)};
    *reinterpret_cast<uint4*>(ub + ((size_t)n * 512 + o) * 512 + d0) =
        *reinterpret_cast<const uint4*>(pk);
}

// ---------------- kPrepX: xb[n][l][d] bf16 <- x[l][n][d] f32 ------------------
__global__ __launch_bounds__(256) void kPrepX(const float* __restrict__ x,
                                              uint16_t* __restrict__ xb) {
    int b = blockIdx.x;
    int tid = threadIdx.x;
    int row = b * 4 + (tid >> 6);    // (l*64 + n)
    int l = row >> 6, n = row & 63;
    int d0 = (tid & 63) * 8;
    const float* src = x + (size_t)row * 512 + d0;
    float4 v0 = *reinterpret_cast<const float4*>(src);
    float4 v1 = *reinterpret_cast<const float4*>(src + 4);
    uint32_t pk[4] = {cvt2(v0.x, v0.y), cvt2(v0.z, v0.w),
                      cvt2(v1.x, v1.y), cvt2(v1.z, v1.w)};
    *reinterpret_cast<uint4*>(xb + ((size_t)n * 512 + l) * 512 + d0) =
        *reinterpret_cast<const uint4*>(pk);
}

// ---------------- kPrepT: ut[n][d][o] <- ub[n][o][d], tiled transpose ---------
__global__ __launch_bounds__(256) void kPrepT(const uint16_t* __restrict__ ub,
                                              uint16_t* __restrict__ ut) {
    __shared__ uint32_t tl[512 * 20];     // 40 KB
    int blk  = blockIdx.x;
    int rest = blk >> 3;                  // 0..127
    int n    = (blk & 7) * 8 + (rest >> 4);
    int d0   = (rest & 15) * 32;
    int tid  = threadIdx.x;

    #pragma unroll
    for (int e = 0; e < 2; ++e) {
        int o = tid * 2 + e;
        const uint16_t* src = ub + ((size_t)n * 512 + o) * 512 + d0;  // 32 bf16
        uint4 q0 = reinterpret_cast<const uint4*>(src)[0];
        uint4 q1 = reinterpret_cast<const uint4*>(src)[1];
        uint4 q2 = reinterpret_cast<const uint4*>(src)[2];
        uint4 q3 = reinterpret_cast<const uint4*>(src)[3];
        int sw = ((o >> 6) & 3) << 2;
        uint32_t* row = tl + o * 20;
        *reinterpret_cast<uint4*>(row + (0  ^ sw)) = q0;
        *reinterpret_cast<uint4*>(row + (4  ^ sw)) = q1;
        *reinterpret_cast<uint4*>(row + (8  ^ sw)) = q2;
        *reinterpret_cast<uint4*>(row + (12 ^ sw)) = q3;
    }
    __syncthreads();

    int d   = tid >> 3;                   // 0..31
    int seg = (tid & 7) * 64;
    int c   = d >> 1;
    int sh  = (d & 1) * 16;
    uint32_t ow[32];
    #pragma unroll
    for (int j = 0; j < 32; ++j) {
        int o0 = seg + 2 * j;
        int sw = ((o0 >> 6) & 3) << 2;
        uint32_t w0 = tl[o0 * 20 + (c ^ sw)];
        uint32_t w1 = tl[(o0 + 1) * 20 + (c ^ sw)];
        ow[j] = ((w0 >> sh) & 0xFFFFu) | (((w1 >> sh) & 0xFFFFu) << 16);
    }
    uint16_t* dst = ut + ((size_t)n * 512 + d0 + d) * 512 + seg;      // 128 B
    #pragma unroll
    for (int q = 0; q < 8; ++q)
        reinterpret_cast<uint4*>(dst)[q] = *reinterpret_cast<const uint4*>(ow + q * 4);
}

// ---------------- pipelined 256^2 GEMM: C = A . B^T, panels [n][512][512] -----
// MODE 1: sigmoid epilogue -> W bf16 [n][l][o].  MODE 2: f32 -> out[l][n][d].
// BK=32, 16 K-steps, 4-buffer LDS rotation, counted vmcnt(8). (round-8 exact)
template<int MODE>
__global__ __launch_bounds__(512) void kGemmP(const uint16_t* __restrict__ A,
                                              const uint16_t* __restrict__ B,
                                              void* __restrict__ outp) {
    __shared__ __align__(16) uint16_t As[4][8192];   // 256 rows x 32 k = 16KB/buf
    __shared__ __align__(16) uint16_t Bs[4][8192];
    int bid = blockIdx.x;                     // XCD n-grouping: xcd=bid&7 owns 8 n's
    int n  = (bid & 7) * 8 + (bid >> 5);
    int t  = (bid >> 3) & 3;
    int l0 = (t >> 1) << 8, c0 = (t & 1) << 8;
    int tid = threadIdx.x, lane = tid & 63, wid = tid >> 6;
    int wr = wid >> 2, wc = wid & 3;          // per-wave out 128x64

    const char* An = (const char*)(A + (size_t)n * 262144);
    const char* Bn = (const char*)(B + (size_t)n * 262144);

    // Staging: slot s = j*512 + tid -> LDS row r=s>>2, lds-chunk c'=s&3.
    // Slot (r,c') sources global chunk cg = c' ^ ((r>>1)&3)  (swizzle involution).
    int s1 = tid, s2 = tid + 512;
    int r1 = s1 >> 2, r2 = s2 >> 2;
    int cg1 = (s1 & 3) ^ ((r1 >> 1) & 3);
    int cg2 = (s2 & 3) ^ ((r2 >> 1) & 3);
    const char* gA1 = An + (size_t)(l0 + r1) * 1024 + cg1 * 16;
    const char* gA2 = An + (size_t)(l0 + r2) * 1024 + cg2 * 16;
    const char* gB1 = Bn + (size_t)(c0 + r1) * 1024 + cg1 * 16;
    const char* gB2 = Bn + (size_t)(c0 + r2) * 1024 + cg2 * 16;

    f32x4 acc[8][4];
    #pragma unroll
    for (int m = 0; m < 8; ++m)
        #pragma unroll
        for (int nf = 0; nf < 4; ++nf) acc[m][nf] = (f32x4)(0.f);

    auto STAGE = [&](int buf, int kt) {
        int ko = kt * 64;                     // 32 k * 2B
        uint16_t* lA = &As[buf][wid * 512];   // wave-uniform base + lane*16 HW
        uint16_t* lB = &Bs[buf][wid * 512];
        __builtin_amdgcn_global_load_lds(
            (const __attribute__((address_space(1))) uint32_t*)(gA1 + ko),
            (__attribute__((address_space(3))) uint32_t*)(lA), 16, 0, 0);
        __builtin_amdgcn_global_load_lds(
            (const __attribute__((address_space(1))) uint32_t*)(gA2 + ko),
            (__attribute__((address_space(3))) uint32_t*)(lA + 4096), 16, 0, 0);
        __builtin_amdgcn_global_load_lds(
            (const __attribute__((address_space(1))) uint32_t*)(gB1 + ko),
            (__attribute__((address_space(3))) uint32_t*)(lB), 16, 0, 0);
        __builtin_amdgcn_global_load_lds(
            (const __attribute__((address_space(1))) uint32_t*)(gB2 + ko),
            (__attribute__((address_space(3))) uint32_t*)(lB + 4096), 16, 0, 0);
    };

    // prologue: stage tiles 0,1,2; require tile 0 complete (8 newest in flight)
    STAGE(0, 0);
    STAGE(1, 1);
    STAGE(2, 2);
    asm volatile("s_waitcnt vmcnt(8)" ::: "memory");
    __builtin_amdgcn_s_barrier();
    __builtin_amdgcn_sched_barrier(0);

    int g = lane >> 4;                        // k-chunk 0..3 (8 bf16 each)
    #pragma unroll
    for (int kt = 0; kt < 16; ++kt) {
        const int cur = kt & 3;
        if (kt < 13) STAGE((kt + 3) & 3, kt + 3);   // issue 3 tiles ahead
        const char* Ac = (const char*)As[cur];
        const char* Bc = (const char*)Bs[cur];
        short8 a[8], bb[4];
        #pragma unroll
        for (int nf = 0; nf < 4; ++nf) {
            int row = wc * 64 + nf * 16 + (lane & 15);
            int off = row * 64 + ((g ^ ((row >> 1) & 3)) << 4);
            bb[nf] = *reinterpret_cast<const short8*>(Bc + off);
        }
        #pragma unroll
        for (int m = 0; m < 8; ++m) {
            int row = wr * 128 + m * 16 + (lane & 15);
            int off = row * 64 + ((g ^ ((row >> 1) & 3)) << 4);
            a[m] = *reinterpret_cast<const short8*>(Ac + off);
        }
        #pragma unroll
        for (int m = 0; m < 8; ++m)
            #pragma unroll
            for (int nf = 0; nf < 4; ++nf)
                acc[m][nf] = __builtin_amdgcn_mfma_f32_16x16x32_bf16(
                    a[m], bb[nf], acc[m][nf], 0, 0, 0);
        // end-of-step: require tile kt+1 resident; keep newest loads in flight
        if (kt < 13) {
            asm volatile("s_waitcnt vmcnt(8)" ::: "memory");
            __builtin_amdgcn_s_barrier();
            __builtin_amdgcn_sched_barrier(0);
        } else if (kt == 13) {
            asm volatile("s_waitcnt vmcnt(4)" ::: "memory");
            __builtin_amdgcn_s_barrier();
            __builtin_amdgcn_sched_barrier(0);
        } else if (kt == 14) {
            asm volatile("s_waitcnt vmcnt(0)" ::: "memory");
            __builtin_amdgcn_s_barrier();
            __builtin_amdgcn_sched_barrier(0);
        }
    }

    if constexpr (MODE == 1) {
        uint16_t* Wn = (uint16_t*)outp + (size_t)n * 262144;
        const float scale = 0.044194173824159216f;   // 1/sqrt(512)
        #pragma unroll
        for (int m = 0; m < 8; ++m) {
            int lrow0 = l0 + wr * 128 + m * 16 + ((lane >> 4) << 2);
            #pragma unroll
            for (int nf = 0; nf < 4; ++nf) {
                int ocol = c0 + wc * 64 + nf * 16 + (lane & 15);
                #pragma unroll
                for (int r = 0; r < 4; ++r) {
                    float aff = acc[m][nf][r] * scale;
                    float w = 1.f / (1.f + __expf(-aff)) - 0.5f;
                    Wn[(size_t)(lrow0 + r) * 512 + ocol] = f2bf(w);
                }
            }
        }
    } else {
        float* On = (float*)outp;
        #pragma unroll
        for (int m = 0; m < 8; ++m) {
            int lrow0 = l0 + wr * 128 + m * 16 + ((lane >> 4) << 2);
            #pragma unroll
            for (int nf = 0; nf < 4; ++nf) {
                int dcol = c0 + wc * 64 + nf * 16 + (lane & 15);
                #pragma unroll
                for (int r = 0; r < 4; ++r)
                    On[((size_t)(lrow0 + r) * 64 + n) * 512 + dcol] = acc[m][nf][r];
            }
        }
    }
}

// ---------------- mid-tier fallbacks -----------------------------------------
__global__ __launch_bounds__(256) void kPrepUp(const float* __restrict__ up,
                                               uint16_t* __restrict__ ub,
                                               uint16_t* __restrict__ ut) {
    __shared__ float tile[64][65];
    int wgid = blockIdx.x;
    int iq = wgid >> 3;
    int n  = (wgid & 7) * 8 + (iq >> 6);
    int r  = iq & 63;
    int o0 = (r >> 3) << 6, d0 = (r & 7) << 6;
    int tid = threadIdx.x;
    int i  = tid >> 2;
    int jq = (tid & 3) << 4;

    const float* src = up + ((size_t)(o0 + i) * 64 + n) * 512 + d0 + jq;
    float v[16];
    #pragma unroll
    for (int c = 0; c < 16; c += 4) {
        float4 q = *reinterpret_cast<const float4*>(src + c);
        v[c] = q.x; v[c+1] = q.y; v[c+2] = q.z; v[c+3] = q.w;
        tile[i][jq+c] = q.x; tile[i][jq+c+1] = q.y;
        tile[i][jq+c+2] = q.z; tile[i][jq+c+3] = q.w;
    }
    uint32_t pk[8];
    if (ub) {
        #pragma unroll
        for (int c = 0; c < 8; ++c) pk[c] = cvt2(v[2*c], v[2*c+1]);
        uint16_t* udst = ub + ((size_t)n * 512 + o0 + i) * 512 + d0 + jq;
        *reinterpret_cast<uint4*>(udst)     = *reinterpret_cast<const uint4*>(pk);
        *reinterpret_cast<uint4*>(udst + 8) = *reinterpret_cast<const uint4*>(pk + 4);
    }
    __syncthreads();
    #pragma unroll
    for (int c = 0; c < 8; ++c) pk[c] = cvt2(tile[jq + 2*c][i], tile[jq + 2*c + 1][i]);
    uint16_t* tdst = ut + ((size_t)n * 512 + d0 + i) * 512 + o0 + jq;
    *reinterpret_cast<uint4*>(tdst)     = *reinterpret_cast<const uint4*>(pk);
    *reinterpret_cast<uint4*>(tdst + 8) = *reinterpret_cast<const uint4*>(pk + 4);
}

__global__ __launch_bounds__(256) void kGemm1f32(const float* __restrict__ x,
                                                 const float* __restrict__ up,
                                                 uint16_t* __restrict__ W) {
    __shared__ uint16_t As[128 * 64];
    __shared__ uint16_t Bs[128 * 64];
    int b   = blockIdx.x;
    int n   = b >> 4;
    int t   = b & 15;
    int l0  = (t >> 2) << 7, o0 = (t & 3) << 7;
    int tid = threadIdx.x, lane = tid & 63, wid = tid >> 6;
    int wr = wid >> 1, wc = wid & 1;

    f32x4 acc[4][4];
    #pragma unroll
    for (int m = 0; m < 4; ++m)
        #pragma unroll
        for (int nf = 0; nf < 4; ++nf) acc[m][nf] = (f32x4)(0.f);

    int srow = tid >> 1;
    int kh   = (tid & 1) * 32;
    int swz  = (srow & 7) << 4;
    const float* aSrc = x  + ((size_t)(l0 + srow) * 64 + n) * 512 + kh;
    const float* bSrc = up + ((size_t)(o0 + srow) * 64 + n) * 512 + kh;

    for (int kt = 0; kt < 8; ++kt) {
        __syncthreads();
        const float* pA = aSrc + kt * 64;
        const float* pB = bSrc + kt * 64;
        #pragma unroll
        for (int c2 = 0; c2 < 4; ++c2) {
            float4 a0 = *reinterpret_cast<const float4*>(pA + c2 * 8);
            float4 a1 = *reinterpret_cast<const float4*>(pA + c2 * 8 + 4);
            float4 b0 = *reinterpret_cast<const float4*>(pB + c2 * 8);
            float4 b1 = *reinterpret_cast<const float4*>(pB + c2 * 8 + 4);
            uint32_t pa[4] = {cvt2(a0.x,a0.y), cvt2(a0.z,a0.w), cvt2(a1.x,a1.y), cvt2(a1.z,a1.w)};
            uint32_t pb[4] = {cvt2(b0.x,b0.y), cvt2(b0.z,b0.w), cvt2(b1.x,b1.y), cvt2(b1.z,b1.w)};
            int off = srow * 128 + (((kh * 2) + c2 * 16) ^ swz);
            *reinterpret_cast<uint4*>((char*)As + off) = *reinterpret_cast<const uint4*>(pa);
            *reinterpret_cast<uint4*>((char*)Bs + off) = *reinterpret_cast<const uint4*>(pb);
        }
        __syncthreads();
        #pragma unroll
        for (int kk = 0; kk < 2; ++kk) {
            short8 a[4], bf[4];
            int kbyte = kk * 64 + ((lane >> 4) * 16);
            #pragma unroll
            for (int m = 0; m < 4; ++m) {
                int row = wr * 64 + m * 16 + (lane & 15);
                int off = row * 128 + (kbyte ^ ((row & 7) << 4));
                a[m] = *reinterpret_cast<const short8*>((char*)As + off);
            }
            #pragma unroll
            for (int nf = 0; nf < 4; ++nf) {
                int row = wc * 64 + nf * 16 + (lane & 15);
                int off = row * 128 + (kbyte ^ ((row & 7) << 4));
                bf[nf] = *reinterpret_cast<const short8*>((char*)Bs + off);
            }
            #pragma unroll
            for (int m = 0; m < 4; ++m)
                #pragma unroll
                for (int nf = 0; nf < 4; ++nf)
                    acc[m][nf] = __builtin_amdgcn_mfma_f32_16x16x32_bf16(
                        a[m], bf[nf], acc[m][nf], 0, 0, 0);
        }
    }
    const float scale = 0.044194173824159216f;
    #pragma unroll
    for (int m = 0; m < 4; ++m) {
        int lrow0 = l0 + wr * 64 + m * 16 + ((lane >> 4) << 2);
        #pragma unroll
        for (int nf = 0; nf < 4; ++nf) {
            int ocol = o0 + wc * 64 + nf * 16 + (lane & 15);
            #pragma unroll
            for (int r = 0; r < 4; ++r) {
                float aff = acc[m][nf][r] * scale;
                float w = 1.f / (1.f + __expf(-aff)) - 0.5f;
                W[((size_t)n * 512 + (lrow0 + r)) * 512 + ocol] = f2bf(w);
            }
        }
    }
}

__global__ __launch_bounds__(256) void kGemm2Mid(const uint16_t* __restrict__ W,
                                                 const uint16_t* __restrict__ ut,
                                                 float* __restrict__ out) {
    __shared__ uint16_t As[8192];
    __shared__ uint16_t Bs[8192];
    int d = blockIdx.x;
    int n  = (d & 7) * 8 + (d >> 7);
    int t  = (d >> 3) & 15;
    int l0 = (t >> 2) << 7, c0 = (t & 3) << 7;
    int tid = threadIdx.x, lane = tid & 63, wid = tid >> 6;
    int wr = wid >> 1, wc = wid & 1;

    const char* An = (const char*)(W  + (size_t)n * 262144);
    const char* Bn = (const char*)(ut + (size_t)n * 262144);
    int rsub  = lane >> 3;
    int sbyte = ((lane & 7) ^ rsub) << 4;
    const char* gA = An + (size_t)(l0 + wid * 32 + rsub) * 1024 + sbyte;
    const char* gB = Bn + (size_t)(c0 + wid * 32 + rsub) * 1024 + sbyte;
    uint16_t* lA = As + wid * 2048;
    uint16_t* lB = Bs + wid * 2048;

    f32x4 acc[4][4];
    #pragma unroll
    for (int m = 0; m < 4; ++m)
        #pragma unroll
        for (int nf = 0; nf < 4; ++nf) acc[m][nf] = (f32x4)(0.f);

    for (int kt = 0; kt < 8; ++kt) {
        if (kt) __syncthreads();
        #pragma unroll
        for (int j = 0; j < 4; ++j) {
            __builtin_amdgcn_global_load_lds(
                (const __attribute__((address_space(1))) uint32_t*)(gA + kt * 128 + j * 8192),
                (__attribute__((address_space(3))) uint32_t*)(lA + j * 512), 16, 0, 0);
            __builtin_amdgcn_global_load_lds(
                (const __attribute__((address_space(1))) uint32_t*)(gB + kt * 128 + j * 8192),
                (__attribute__((address_space(3))) uint32_t*)(lB + j * 512), 16, 0, 0);
        }
        __syncthreads();
        #pragma unroll
        for (int kk = 0; kk < 2; ++kk) {
            short8 a[4], bb[4];
            int kbyte = kk * 64 + ((lane >> 4) * 16);
            #pragma unroll
            for (int m = 0; m < 4; ++m) {
                int row = wr * 64 + m * 16 + (lane & 15);
                int off = row * 128 + (kbyte ^ ((row & 7) << 4));
                a[m] = *reinterpret_cast<const short8*>((const char*)As + off);
            }
            #pragma unroll
            for (int nf = 0; nf < 4; ++nf) {
                int row = wc * 64 + nf * 16 + (lane & 15);
                int off = row * 128 + (kbyte ^ ((row & 7) << 4));
                bb[nf] = *reinterpret_cast<const short8*>((const char*)Bs + off);
            }
            #pragma unroll
            for (int m = 0; m < 4; ++m)
                #pragma unroll
                for (int nf = 0; nf < 4; ++nf)
                    acc[m][nf] = __builtin_amdgcn_mfma_f32_16x16x32_bf16(
                        a[m], bb[nf], acc[m][nf], 0, 0, 0);
        }
    }
    #pragma unroll
    for (int m = 0; m < 4; ++m) {
        int lrow0 = l0 + wr * 64 + m * 16 + ((lane >> 4) << 2);
        #pragma unroll
        for (int nf = 0; nf < 4; ++nf) {
            int dcol = c0 + wc * 64 + nf * 16 + (lane & 15);
            #pragma unroll
            for (int r = 0; r < 4; ++r)
                out[((size_t)(lrow0 + r) * 64 + n) * 512 + dcol] = acc[m][nf][r];
        }
    }
}

__global__ __launch_bounds__(256) void kNaive(const float* __restrict__ x,
                                              const float* __restrict__ up,
                                              float* __restrict__ out) {
    __shared__ float xr[512];
    __shared__ float w[512];
    int b = blockIdx.x;
    int l = b >> 6, n = b & 63;
    int tid = threadIdx.x;
    const float* xrow = x + ((size_t)l * 64 + n) * 512;
    xr[tid] = xrow[tid];
    xr[tid + 256] = xrow[tid + 256];
    __syncthreads();
    const float scale = 0.044194173824159216f;
    #pragma unroll
    for (int oo = 0; oo < 2; ++oo) {
        int o = tid + oo * 256;
        const float* ur = up + ((size_t)o * 64 + n) * 512;
        float s = 0.f;
        for (int dd = 0; dd < 512; ++dd) s += xr[dd] * ur[dd];
        w[o] = 1.f / (1.f + __expf(-s * scale)) - 0.5f;
    }
    __syncthreads();
    #pragma unroll
    for (int dd = 0; dd < 2; ++dd) {
        int d = tid + dd * 256;
        float f = 0.f;
        for (int o = 0; o < 512; ++o)
            f += w[o] * up[((size_t)o * 64 + n) * 512 + d];
        out[((size_t)l * 64 + n) * 512 + d] = f;
    }
}

extern "C" void kernel_launch(void* const* d_in, const int* in_sizes, int n_in,
                              void* d_out, int out_size, void* d_ws, size_t ws_size,
                              hipStream_t stream) {
    const float* x  = (const float*)d_in[0];
    const float* up = (const float*)d_in[1];
    float* out = (float*)d_out;

    const size_t MB32 = (size_t)64 * 512 * 512 * 2;   // one bf16 panel set
    if (ws_size >= 4 * MB32) {
        uint16_t* XB = (uint16_t*)d_ws;
        uint16_t* UB = XB + 16777216;
        uint16_t* UT = UB + 16777216;
        uint16_t* W  = UT + 16777216;
        kPrepU<<<8192, 256, 0, stream>>>(up, UB);
        kPrepX<<<8192, 256, 0, stream>>>(x, XB);
        kPrepT<<<1024, 256, 0, stream>>>(UB, UT);
        kGemmP<1><<<256, 512, 0, stream>>>(XB, UB, W);
        kGemmP<2><<<256, 512, 0, stream>>>(W, UT, out);
    } else if (ws_size >= 2 * MB32) {
        uint16_t* UT = (uint16_t*)d_ws;
        uint16_t* W  = UT + 16777216;
        kPrepUp<<<4096, 256, 0, stream>>>(up, nullptr, UT);
        kGemm1f32<<<1024, 256, 0, stream>>>(x, up, W);
        kGemm2Mid<<<1024, 256, 0, stream>>>(W, UT, out);
    } else {
        kNaive<<<512 * 64, 256, 0, stream>>>(x, up, out);
    }
}

// Round 13
// 105.085 us; speedup vs baseline: 1.1219x; 1.1219x over previous
//
#include <hip/hip_runtime.h>
#include <hip/hip_bf16.h>
#include <stdint.h>

// x[L=512][N=64][D=512] f32, upfold[O=512][N=64][D=512] f32
//   S[l,o,n] = sum_d x[l,n,d]*up[o,n,d] / sqrt(512);  W = sigmoid(S)-0.5
//   out[l,n,d] = sum_o W[l,o,n] * up[o,n,d]   (f32)
//
// Round 13 = round-8 pipeline (best, 108us) with kPrepUp2 replacing kPrepUp:
//   kPrepUp2: up -> ub[n][o][d] + ut[n][d][o] bf16, 128o x 256d tiles.
//     Segments per instruction: reads 1KB, ub writes 512B, ut writes 256B
//     (round-8 version was 256B/128B/128B scattered -> 3.4 TB/s).
//   kPrepX : xb[n][l][d] bf16 <- x
//   kGemmP<1>: W[n][l][o] = sig(xb . ub^T /sqrt(D)) - 0.5  (round-8 exact)
//   kGemmP<2>: out[l][n][d] = W . ut^T                     (round-8 exact)
// GEMM: 256^2 tile, 8 waves, BK=32, 4 LDS buffers, counted vmcnt(8) (T4),
// swizzle involution chunk^=(row>>1)&3, XCD n-grouping. No setprio (r9 null).

typedef __attribute__((ext_vector_type(8))) short short8;   // 8 bf16
typedef __attribute__((ext_vector_type(4))) float f32x4;

__device__ __forceinline__ uint16_t f2bf(float f) {
    uint32_t u = __builtin_bit_cast(uint32_t, f);
    uint32_t r = u + 0x7FFFu + ((u >> 16) & 1u);   // RNE
    return (uint16_t)(r >> 16);
}
__device__ __forceinline__ uint32_t cvt2(float a, float b) {
    return (uint32_t)f2bf(a) | ((uint32_t)f2bf(b) << 16);
}

// ---------------- kPrepUp2: ub[n][o][d] + ut[n][d][o] <- up[o][n][d] ----------
// 512 blocks (64 n x 4 og x 2 dg) x 256 thr. LDS tile 128o x 256d bf16,
// row stride 272 (16B-aligned), chunk-XOR swizzle ch^((o>>3)&15) so the
// phase-B column gather spreads banks (~2-way).
__global__ __launch_bounds__(256) void kPrepUp2(const float* __restrict__ up,
                                                uint16_t* __restrict__ ub,
                                                uint16_t* __restrict__ ut) {
    __shared__ uint16_t tl[128 * 272];    // 68 KB
    int bid = blockIdx.x;
    int n  = bid >> 3;
    int o0 = ((bid >> 1) & 3) * 128;
    int d0 = (bid & 1) * 256;
    int tid = threadIdx.x;

    // Phase A: 16 passes x 8 rows; 32 lanes x 8 f32 per row (1KB read).
    int rp = tid >> 5;                    // row-in-pass 0..7
    int ch = tid & 31;                    // 8-elem d-chunk 0..31
    #pragma unroll
    for (int p = 0; p < 16; ++p) {
        int o = p * 8 + rp;               // local o 0..127
        const float* src = up + ((size_t)(o0 + o) * 64 + n) * 512 + d0 + ch * 8;
        float4 v0 = *reinterpret_cast<const float4*>(src);
        float4 v1 = *reinterpret_cast<const float4*>(src + 4);
        uint32_t pk[4] = {cvt2(v0.x, v0.y), cvt2(v0.z, v0.w),
                          cvt2(v1.x, v1.y), cvt2(v1.z, v1.w)};
        *reinterpret_cast<uint4*>(ub + ((size_t)n * 512 + o0 + o) * 512 + d0 + ch * 8) =
            *reinterpret_cast<const uint4*>(pk);
        int chs = ch ^ ((o >> 3) & 15);   // swizzled chunk for LDS
        *reinterpret_cast<uint4*>(&tl[o * 272 + chs * 8]) =
            *reinterpret_cast<const uint4*>(pk);
    }
    __syncthreads();

    // Phase B: ut rows. 16 passes x 16 d-rows; 16 lanes x 16B per row (256B).
    int oc = (tid & 15) * 8;              // o-chunk base
    int dr = tid >> 4;                    // d row-in-pass 0..15
    #pragma unroll
    for (int q = 0; q < 16; ++q) {
        int d = q * 16 + dr;              // local d 0..255
        uint16_t g[8];
        #pragma unroll
        for (int j = 0; j < 8; ++j) {
            int o = oc + j;
            int chs = (d >> 3) ^ ((o >> 3) & 15);
            g[j] = tl[o * 272 + chs * 8 + (d & 7)];
        }
        *reinterpret_cast<uint4*>(ut + ((size_t)n * 512 + d0 + d) * 512 + o0 + oc) =
            *reinterpret_cast<const uint4*>(g);
    }
}

// ---------------- kPrepX: xb[n][l][d] bf16 <- x[l][n][d] f32 ------------------
__global__ __launch_bounds__(256) void kPrepX(const float* __restrict__ x,
                                              uint16_t* __restrict__ xb) {
    int b = blockIdx.x;
    int tid = threadIdx.x;
    int row = b * 4 + (tid >> 6);    // (l*64 + n)
    int l = row >> 6, n = row & 63;
    int d0 = (tid & 63) * 8;
    const float* src = x + (size_t)row * 512 + d0;
    float4 v0 = *reinterpret_cast<const float4*>(src);
    float4 v1 = *reinterpret_cast<const float4*>(src + 4);
    uint32_t pk[4] = {cvt2(v0.x, v0.y), cvt2(v0.z, v0.w),
                      cvt2(v1.x, v1.y), cvt2(v1.z, v1.w)};
    *reinterpret_cast<uint4*>(xb + ((size_t)n * 512 + l) * 512 + d0) =
        *reinterpret_cast<const uint4*>(pk);
}

// ---------------- pipelined 256^2 GEMM: C = A . B^T, panels [n][512][512] -----
// MODE 1: sigmoid epilogue -> W bf16 [n][l][o].  MODE 2: f32 -> out[l][n][d].
// BK=32, 16 K-steps, 4-buffer LDS rotation, counted vmcnt(8). (round-8 exact)
template<int MODE>
__global__ __launch_bounds__(512) void kGemmP(const uint16_t* __restrict__ A,
                                              const uint16_t* __restrict__ B,
                                              void* __restrict__ outp) {
    __shared__ __align__(16) uint16_t As[4][8192];   // 256 rows x 32 k = 16KB/buf
    __shared__ __align__(16) uint16_t Bs[4][8192];
    int bid = blockIdx.x;                     // XCD n-grouping: xcd=bid&7 owns 8 n's
    int n  = (bid & 7) * 8 + (bid >> 5);
    int t  = (bid >> 3) & 3;
    int l0 = (t >> 1) << 8, c0 = (t & 1) << 8;
    int tid = threadIdx.x, lane = tid & 63, wid = tid >> 6;
    int wr = wid >> 2, wc = wid & 3;          // per-wave out 128x64

    const char* An = (const char*)(A + (size_t)n * 262144);
    const char* Bn = (const char*)(B + (size_t)n * 262144);

    // Staging: slot s = j*512 + tid -> LDS row r=s>>2, lds-chunk c'=s&3.
    // Slot (r,c') sources global chunk cg = c' ^ ((r>>1)&3)  (swizzle involution).
    int s1 = tid, s2 = tid + 512;
    int r1 = s1 >> 2, r2 = s2 >> 2;
    int cg1 = (s1 & 3) ^ ((r1 >> 1) & 3);
    int cg2 = (s2 & 3) ^ ((r2 >> 1) & 3);
    const char* gA1 = An + (size_t)(l0 + r1) * 1024 + cg1 * 16;
    const char* gA2 = An + (size_t)(l0 + r2) * 1024 + cg2 * 16;
    const char* gB1 = Bn + (size_t)(c0 + r1) * 1024 + cg1 * 16;
    const char* gB2 = Bn + (size_t)(c0 + r2) * 1024 + cg2 * 16;

    f32x4 acc[8][4];
    #pragma unroll
    for (int m = 0; m < 8; ++m)
        #pragma unroll
        for (int nf = 0; nf < 4; ++nf) acc[m][nf] = (f32x4)(0.f);

    auto STAGE = [&](int buf, int kt) {
        int ko = kt * 64;                     // 32 k * 2B
        uint16_t* lA = &As[buf][wid * 512];   // wave-uniform base + lane*16 HW
        uint16_t* lB = &Bs[buf][wid * 512];
        __builtin_amdgcn_global_load_lds(
            (const __attribute__((address_space(1))) uint32_t*)(gA1 + ko),
            (__attribute__((address_space(3))) uint32_t*)(lA), 16, 0, 0);
        __builtin_amdgcn_global_load_lds(
            (const __attribute__((address_space(1))) uint32_t*)(gA2 + ko),
            (__attribute__((address_space(3))) uint32_t*)(lA + 4096), 16, 0, 0);
        __builtin_amdgcn_global_load_lds(
            (const __attribute__((address_space(1))) uint32_t*)(gB1 + ko),
            (__attribute__((address_space(3))) uint32_t*)(lB), 16, 0, 0);
        __builtin_amdgcn_global_load_lds(
            (const __attribute__((address_space(1))) uint32_t*)(gB2 + ko),
            (__attribute__((address_space(3))) uint32_t*)(lB + 4096), 16, 0, 0);
    };

    // prologue: stage tiles 0,1,2; require tile 0 complete (8 newest in flight)
    STAGE(0, 0);
    STAGE(1, 1);
    STAGE(2, 2);
    asm volatile("s_waitcnt vmcnt(8)" ::: "memory");
    __builtin_amdgcn_s_barrier();
    __builtin_amdgcn_sched_barrier(0);

    int g = lane >> 4;                        // k-chunk 0..3 (8 bf16 each)
    #pragma unroll
    for (int kt = 0; kt < 16; ++kt) {
        const int cur = kt & 3;
        if (kt < 13) STAGE((kt + 3) & 3, kt + 3);   // issue 3 tiles ahead
        const char* Ac = (const char*)As[cur];
        const char* Bc = (const char*)Bs[cur];
        short8 a[8], bb[4];
        #pragma unroll
        for (int nf = 0; nf < 4; ++nf) {
            int row = wc * 64 + nf * 16 + (lane & 15);
            int off = row * 64 + ((g ^ ((row >> 1) & 3)) << 4);
            bb[nf] = *reinterpret_cast<const short8*>(Bc + off);
        }
        #pragma unroll
        for (int m = 0; m < 8; ++m) {
            int row = wr * 128 + m * 16 + (lane & 15);
            int off = row * 64 + ((g ^ ((row >> 1) & 3)) << 4);
            a[m] = *reinterpret_cast<const short8*>(Ac + off);
        }
        #pragma unroll
        for (int m = 0; m < 8; ++m)
            #pragma unroll
            for (int nf = 0; nf < 4; ++nf)
                acc[m][nf] = __builtin_amdgcn_mfma_f32_16x16x32_bf16(
                    a[m], bb[nf], acc[m][nf], 0, 0, 0);
        // end-of-step: require tile kt+1 resident; keep newest loads in flight
        if (kt < 13) {
            asm volatile("s_waitcnt vmcnt(8)" ::: "memory");
            __builtin_amdgcn_s_barrier();
            __builtin_amdgcn_sched_barrier(0);
        } else if (kt == 13) {
            asm volatile("s_waitcnt vmcnt(4)" ::: "memory");
            __builtin_amdgcn_s_barrier();
            __builtin_amdgcn_sched_barrier(0);
        } else if (kt == 14) {
            asm volatile("s_waitcnt vmcnt(0)" ::: "memory");
            __builtin_amdgcn_s_barrier();
            __builtin_amdgcn_sched_barrier(0);
        }
    }

    if constexpr (MODE == 1) {
        uint16_t* Wn = (uint16_t*)outp + (size_t)n * 262144;
        const float scale = 0.044194173824159216f;   // 1/sqrt(512)
        #pragma unroll
        for (int m = 0; m < 8; ++m) {
            int lrow0 = l0 + wr * 128 + m * 16 + ((lane >> 4) << 2);
            #pragma unroll
            for (int nf = 0; nf < 4; ++nf) {
                int ocol = c0 + wc * 64 + nf * 16 + (lane & 15);
                #pragma unroll
                for (int r = 0; r < 4; ++r) {
                    float aff = acc[m][nf][r] * scale;
                    float w = 1.f / (1.f + __expf(-aff)) - 0.5f;
                    Wn[(size_t)(lrow0 + r) * 512 + ocol] = f2bf(w);
                }
            }
        }
    } else {
        float* On = (float*)outp;
        #pragma unroll
        for (int m = 0; m < 8; ++m) {
            int lrow0 = l0 + wr * 128 + m * 16 + ((lane >> 4) << 2);
            #pragma unroll
            for (int nf = 0; nf < 4; ++nf) {
                int dcol = c0 + wc * 64 + nf * 16 + (lane & 15);
                #pragma unroll
                for (int r = 0; r < 4; ++r)
                    On[((size_t)(lrow0 + r) * 64 + n) * 512 + dcol] = acc[m][nf][r];
            }
        }
    }
}

// ---------------- naive fallback ---------------------------------------------
__global__ __launch_bounds__(256) void kNaive(const float* __restrict__ x,
                                              const float* __restrict__ up,
                                              float* __restrict__ out) {
    __shared__ float xr[512];
    __shared__ float w[512];
    int b = blockIdx.x;
    int l = b >> 6, n = b & 63;
    int tid = threadIdx.x;
    const float* xrow = x + ((size_t)l * 64 + n) * 512;
    xr[tid] = xrow[tid];
    xr[tid + 256] = xrow[tid + 256];
    __syncthreads();
    const float scale = 0.044194173824159216f;
    #pragma unroll
    for (int oo = 0; oo < 2; ++oo) {
        int o = tid + oo * 256;
        const float* ur = up + ((size_t)o * 64 + n) * 512;
        float s = 0.f;
        for (int dd = 0; dd < 512; ++dd) s += xr[dd] * ur[dd];
        w[o] = 1.f / (1.f + __expf(-s * scale)) - 0.5f;
    }
    __syncthreads();
    #pragma unroll
    for (int dd = 0; dd < 2; ++dd) {
        int d = tid + dd * 256;
        float f = 0.f;
        for (int o = 0; o < 512; ++o)
            f += w[o] * up[((size_t)o * 64 + n) * 512 + d];
        out[((size_t)l * 64 + n) * 512 + d] = f;
    }
}

extern "C" void kernel_launch(void* const* d_in, const int* in_sizes, int n_in,
                              void* d_out, int out_size, void* d_ws, size_t ws_size,
                              hipStream_t stream) {
    const float* x  = (const float*)d_in[0];
    const float* up = (const float*)d_in[1];
    float* out = (float*)d_out;

    const size_t MB32 = (size_t)64 * 512 * 512 * 2;   // one bf16 panel set
    if (ws_size >= 4 * MB32) {
        uint16_t* XB = (uint16_t*)d_ws;
        uint16_t* UB = XB + 16777216;
        uint16_t* UT = UB + 16777216;
        uint16_t* W  = UT + 16777216;
        kPrepUp2<<<512, 256, 0, stream>>>(up, UB, UT);
        kPrepX<<<8192, 256, 0, stream>>>(x, XB);
        kGemmP<1><<<256, 512, 0, stream>>>(XB, UB, W);
        kGemmP<2><<<256, 512, 0, stream>>>(W, UT, out);
    } else {
        kNaive<<<512 * 64, 256, 0, stream>>>(x, up, out);
    }
}

// Round 14
// 99.814 us; speedup vs baseline: 1.1812x; 1.0528x over previous
//
#include <hip/hip_runtime.h>
#include <hip/hip_bf16.h>
#include <stdint.h>

// x[L=512][N=64][D=512] f32, upfold[O=512][N=64][D=512] f32
//   S[l,o,n] = sum_d x[l,n,d]*up[o,n,d] / sqrt(512);  W = sigmoid(S)-0.5
//   out[l,n,d] = sum_o W[l,o,n] * up[o,n,d]   (f32)
//
// Round 14 = round-13 with kPrepX FUSED into kPrepUp3 as phase C:
//   kPrepUp3: 512 blocks (n, o-group, d-group):
//     A: up tile 128o x 256d -> ub bf16 + LDS (swizzled)
//     B: LDS -> ut bf16 (256B-segment writes)
//     C: 64 x-rows -> xb bf16 (pure streaming, no LDS, no barrier)
//   kGemmP<1>: W[n][l][o] = sig(xb . ub^T /sqrt(D)) - 0.5  (round-8 exact)
//   kGemmP<2>: out[l][n][d] = W . ut^T                     (round-8 exact)
// 3 launches total; prep BW stays saturated across the old kernel boundary.

typedef __attribute__((ext_vector_type(8))) short short8;   // 8 bf16
typedef __attribute__((ext_vector_type(4))) float f32x4;

__device__ __forceinline__ uint16_t f2bf(float f) {
    uint32_t u = __builtin_bit_cast(uint32_t, f);
    uint32_t r = u + 0x7FFFu + ((u >> 16) & 1u);   // RNE
    return (uint16_t)(r >> 16);
}
__device__ __forceinline__ uint32_t cvt2(float a, float b) {
    return (uint32_t)f2bf(a) | ((uint32_t)f2bf(b) << 16);
}

// ---------------- kPrepUp3: ub + ut + xb from up, x ---------------------------
// 512 blocks (64 n x 4 og x 2 dg) x 256 thr. LDS tile 128o x 256d bf16,
// row stride 272, chunk-XOR swizzle ch^((o>>3)&15).
__global__ __launch_bounds__(256) void kPrepUp3(const float* __restrict__ up,
                                                const float* __restrict__ x,
                                                uint16_t* __restrict__ ub,
                                                uint16_t* __restrict__ ut,
                                                uint16_t* __restrict__ xb) {
    __shared__ uint16_t tl[128 * 272];    // 68 KB
    int bid = blockIdx.x;
    int n   = bid >> 3;
    int sub = bid & 7;
    int o0 = (sub >> 1) * 128;
    int d0 = (sub & 1) * 256;
    int tid = threadIdx.x;

    // Phase A: up -> ub + LDS. 16 passes x 8 rows; 32 lanes x 8 f32 (1KB read).
    int rp = tid >> 5;                    // row-in-pass 0..7
    int ch = tid & 31;                    // 8-elem d-chunk 0..31
    #pragma unroll
    for (int p = 0; p < 16; ++p) {
        int o = p * 8 + rp;               // local o 0..127
        const float* src = up + ((size_t)(o0 + o) * 64 + n) * 512 + d0 + ch * 8;
        float4 v0 = *reinterpret_cast<const float4*>(src);
        float4 v1 = *reinterpret_cast<const float4*>(src + 4);
        uint32_t pk[4] = {cvt2(v0.x, v0.y), cvt2(v0.z, v0.w),
                          cvt2(v1.x, v1.y), cvt2(v1.z, v1.w)};
        *reinterpret_cast<uint4*>(ub + ((size_t)n * 512 + o0 + o) * 512 + d0 + ch * 8) =
            *reinterpret_cast<const uint4*>(pk);
        int chs = ch ^ ((o >> 3) & 15);   // swizzled chunk for LDS
        *reinterpret_cast<uint4*>(&tl[o * 272 + chs * 8]) =
            *reinterpret_cast<const uint4*>(pk);
    }
    __syncthreads();

    // Phase B: LDS -> ut rows. 16 passes x 16 d-rows; 16 lanes x 16B (256B).
    int oc = (tid & 15) * 8;              // o-chunk base
    int dr = tid >> 4;                    // d row-in-pass 0..15
    #pragma unroll
    for (int q = 0; q < 16; ++q) {
        int d = q * 16 + dr;              // local d 0..255
        uint16_t g[8];
        #pragma unroll
        for (int j = 0; j < 8; ++j) {
            int o = oc + j;
            int chs = (d >> 3) ^ ((o >> 3) & 15);
            g[j] = tl[o * 272 + chs * 8 + (d & 7)];
        }
        *reinterpret_cast<uint4*>(ut + ((size_t)n * 512 + d0 + d) * 512 + o0 + oc) =
            *reinterpret_cast<const uint4*>(g);
    }

    // Phase C: x -> xb, 64 l-rows for this (n, sub). No LDS, no barrier.
    // 16 passes x 4 rows; 64 lanes x 8 f32 per row (2KB read, 1KB write).
    int rl = tid >> 6;                    // row-in-pass 0..3
    int cx = tid & 63;                    // 8-elem d-chunk 0..63
    #pragma unroll
    for (int p = 0; p < 16; ++p) {
        int l = sub * 64 + p * 4 + rl;
        const float* src = x + ((size_t)l * 64 + n) * 512 + cx * 8;
        float4 v0 = *reinterpret_cast<const float4*>(src);
        float4 v1 = *reinterpret_cast<const float4*>(src + 4);
        uint32_t pk[4] = {cvt2(v0.x, v0.y), cvt2(v0.z, v0.w),
                          cvt2(v1.x, v1.y), cvt2(v1.z, v1.w)};
        *reinterpret_cast<uint4*>(xb + ((size_t)n * 512 + l) * 512 + cx * 8) =
            *reinterpret_cast<const uint4*>(pk);
    }
}

// ---------------- pipelined 256^2 GEMM: C = A . B^T, panels [n][512][512] -----
// MODE 1: sigmoid epilogue -> W bf16 [n][l][o].  MODE 2: f32 -> out[l][n][d].
// BK=32, 16 K-steps, 4-buffer LDS rotation, counted vmcnt(8). (round-8 exact)
template<int MODE>
__global__ __launch_bounds__(512) void kGemmP(const uint16_t* __restrict__ A,
                                              const uint16_t* __restrict__ B,
                                              void* __restrict__ outp) {
    __shared__ __align__(16) uint16_t As[4][8192];   // 256 rows x 32 k = 16KB/buf
    __shared__ __align__(16) uint16_t Bs[4][8192];
    int bid = blockIdx.x;                     // XCD n-grouping: xcd=bid&7 owns 8 n's
    int n  = (bid & 7) * 8 + (bid >> 5);
    int t  = (bid >> 3) & 3;
    int l0 = (t >> 1) << 8, c0 = (t & 1) << 8;
    int tid = threadIdx.x, lane = tid & 63, wid = tid >> 6;
    int wr = wid >> 2, wc = wid & 3;          // per-wave out 128x64

    const char* An = (const char*)(A + (size_t)n * 262144);
    const char* Bn = (const char*)(B + (size_t)n * 262144);

    int s1 = tid, s2 = tid + 512;
    int r1 = s1 >> 2, r2 = s2 >> 2;
    int cg1 = (s1 & 3) ^ ((r1 >> 1) & 3);
    int cg2 = (s2 & 3) ^ ((r2 >> 1) & 3);
    const char* gA1 = An + (size_t)(l0 + r1) * 1024 + cg1 * 16;
    const char* gA2 = An + (size_t)(l0 + r2) * 1024 + cg2 * 16;
    const char* gB1 = Bn + (size_t)(c0 + r1) * 1024 + cg1 * 16;
    const char* gB2 = Bn + (size_t)(c0 + r2) * 1024 + cg2 * 16;

    f32x4 acc[8][4];
    #pragma unroll
    for (int m = 0; m < 8; ++m)
        #pragma unroll
        for (int nf = 0; nf < 4; ++nf) acc[m][nf] = (f32x4)(0.f);

    auto STAGE = [&](int buf, int kt) {
        int ko = kt * 64;                     // 32 k * 2B
        uint16_t* lA = &As[buf][wid * 512];   // wave-uniform base + lane*16 HW
        uint16_t* lB = &Bs[buf][wid * 512];
        __builtin_amdgcn_global_load_lds(
            (const __attribute__((address_space(1))) uint32_t*)(gA1 + ko),
            (__attribute__((address_space(3))) uint32_t*)(lA), 16, 0, 0);
        __builtin_amdgcn_global_load_lds(
            (const __attribute__((address_space(1))) uint32_t*)(gA2 + ko),
            (__attribute__((address_space(3))) uint32_t*)(lA + 4096), 16, 0, 0);
        __builtin_amdgcn_global_load_lds(
            (const __attribute__((address_space(1))) uint32_t*)(gB1 + ko),
            (__attribute__((address_space(3))) uint32_t*)(lB), 16, 0, 0);
        __builtin_amdgcn_global_load_lds(
            (const __attribute__((address_space(1))) uint32_t*)(gB2 + ko),
            (__attribute__((address_space(3))) uint32_t*)(lB + 4096), 16, 0, 0);
    };

    STAGE(0, 0);
    STAGE(1, 1);
    STAGE(2, 2);
    asm volatile("s_waitcnt vmcnt(8)" ::: "memory");
    __builtin_amdgcn_s_barrier();
    __builtin_amdgcn_sched_barrier(0);

    int g = lane >> 4;                        // k-chunk 0..3 (8 bf16 each)
    #pragma unroll
    for (int kt = 0; kt < 16; ++kt) {
        const int cur = kt & 3;
        if (kt < 13) STAGE((kt + 3) & 3, kt + 3);   // issue 3 tiles ahead
        const char* Ac = (const char*)As[cur];
        const char* Bc = (const char*)Bs[cur];
        short8 a[8], bb[4];
        #pragma unroll
        for (int nf = 0; nf < 4; ++nf) {
            int row = wc * 64 + nf * 16 + (lane & 15);
            int off = row * 64 + ((g ^ ((row >> 1) & 3)) << 4);
            bb[nf] = *reinterpret_cast<const short8*>(Bc + off);
        }
        #pragma unroll
        for (int m = 0; m < 8; ++m) {
            int row = wr * 128 + m * 16 + (lane & 15);
            int off = row * 64 + ((g ^ ((row >> 1) & 3)) << 4);
            a[m] = *reinterpret_cast<const short8*>(Ac + off);
        }
        #pragma unroll
        for (int m = 0; m < 8; ++m)
            #pragma unroll
            for (int nf = 0; nf < 4; ++nf)
                acc[m][nf] = __builtin_amdgcn_mfma_f32_16x16x32_bf16(
                    a[m], bb[nf], acc[m][nf], 0, 0, 0);
        if (kt < 13) {
            asm volatile("s_waitcnt vmcnt(8)" ::: "memory");
            __builtin_amdgcn_s_barrier();
            __builtin_amdgcn_sched_barrier(0);
        } else if (kt == 13) {
            asm volatile("s_waitcnt vmcnt(4)" ::: "memory");
            __builtin_amdgcn_s_barrier();
            __builtin_amdgcn_sched_barrier(0);
        } else if (kt == 14) {
            asm volatile("s_waitcnt vmcnt(0)" ::: "memory");
            __builtin_amdgcn_s_barrier();
            __builtin_amdgcn_sched_barrier(0);
        }
    }

    if constexpr (MODE == 1) {
        uint16_t* Wn = (uint16_t*)outp + (size_t)n * 262144;
        const float scale = 0.044194173824159216f;   // 1/sqrt(512)
        #pragma unroll
        for (int m = 0; m < 8; ++m) {
            int lrow0 = l0 + wr * 128 + m * 16 + ((lane >> 4) << 2);
            #pragma unroll
            for (int nf = 0; nf < 4; ++nf) {
                int ocol = c0 + wc * 64 + nf * 16 + (lane & 15);
                #pragma unroll
                for (int r = 0; r < 4; ++r) {
                    float aff = acc[m][nf][r] * scale;
                    float w = 1.f / (1.f + __expf(-aff)) - 0.5f;
                    Wn[(size_t)(lrow0 + r) * 512 + ocol] = f2bf(w);
                }
            }
        }
    } else {
        float* On = (float*)outp;
        #pragma unroll
        for (int m = 0; m < 8; ++m) {
            int lrow0 = l0 + wr * 128 + m * 16 + ((lane >> 4) << 2);
            #pragma unroll
            for (int nf = 0; nf < 4; ++nf) {
                int dcol = c0 + wc * 64 + nf * 16 + (lane & 15);
                #pragma unroll
                for (int r = 0; r < 4; ++r)
                    On[((size_t)(lrow0 + r) * 64 + n) * 512 + dcol] = acc[m][nf][r];
            }
        }
    }
}

// ---------------- naive fallback ---------------------------------------------
__global__ __launch_bounds__(256) void kNaive(const float* __restrict__ x,
                                              const float* __restrict__ up,
                                              float* __restrict__ out) {
    __shared__ float xr[512];
    __shared__ float w[512];
    int b = blockIdx.x;
    int l = b >> 6, n = b & 63;
    int tid = threadIdx.x;
    const float* xrow = x + ((size_t)l * 64 + n) * 512;
    xr[tid] = xrow[tid];
    xr[tid + 256] = xrow[tid + 256];
    __syncthreads();
    const float scale = 0.044194173824159216f;
    #pragma unroll
    for (int oo = 0; oo < 2; ++oo) {
        int o = tid + oo * 256;
        const float* ur = up + ((size_t)o * 64 + n) * 512;
        float s = 0.f;
        for (int dd = 0; dd < 512; ++dd) s += xr[dd] * ur[dd];
        w[o] = 1.f / (1.f + __expf(-s * scale)) - 0.5f;
    }
    __syncthreads();
    #pragma unroll
    for (int dd = 0; dd < 2; ++dd) {
        int d = tid + dd * 256;
        float f = 0.f;
        for (int o = 0; o < 512; ++o)
            f += w[o] * up[((size_t)o * 64 + n) * 512 + d];
        out[((size_t)l * 64 + n) * 512 + d] = f;
    }
}

extern "C" void kernel_launch(void* const* d_in, const int* in_sizes, int n_in,
                              void* d_out, int out_size, void* d_ws, size_t ws_size,
                              hipStream_t stream) {
    const float* x  = (const float*)d_in[0];
    const float* up = (const float*)d_in[1];
    float* out = (float*)d_out;

    const size_t MB32 = (size_t)64 * 512 * 512 * 2;   // one bf16 panel set
    if (ws_size >= 4 * MB32) {
        uint16_t* XB = (uint16_t*)d_ws;
        uint16_t* UB = XB + 16777216;
        uint16_t* UT = UB + 16777216;
        uint16_t* W  = UT + 16777216;
        kPrepUp3<<<512, 256, 0, stream>>>(up, x, UB, UT, XB);
        kGemmP<1><<<256, 512, 0, stream>>>(XB, UB, W);
        kGemmP<2><<<256, 512, 0, stream>>>(W, UT, out);
    } else {
        kNaive<<<512 * 64, 256, 0, stream>>>(x, up, out);
    }
}